// Round 1
// baseline (494.865 us; speedup 1.0000x reference)
//
#include <hip/hip_runtime.h>

#define NPTS  2048
#define BATCH 4
#define NBP   8192      // BATCH*NPTS
#define MROWS 24576     // NBP*3
#define KNN_K 16

static __device__ __forceinline__ unsigned long long umin64(unsigned long long a, unsigned long long b) {
    return a < b ? a : b;
}

// ---------------------------------------------------------------------------
// transpose input x (B,3,N) -> x0cm[(b*N+n)*3+v]
// ---------------------------------------------------------------------------
__global__ void xpose_kernel(const float* __restrict__ x, float* __restrict__ x0cm)
{
    int i = blockIdx.x * 256 + threadIdx.x;   // over MROWS
    if (i >= MROWS) return;
    int v = i % 3;
    int bn = i / 3;
    int b = bn >> 11;
    int n = bn & (NPTS - 1);
    x0cm[i] = x[(b * 3 + v) * NPTS + n];
}

// ---------------------------------------------------------------------------
// KNN: one block per (b,n); 256 threads scan 2048 candidates, 16 rounds of
// block-wide u64-min selection. Packed key = monotone(float d2) << 32 | m
// -> exact top_k tie-breaking (lowest index wins on equal d2).
// ---------------------------------------------------------------------------
__global__ __launch_bounds__(256) void knn_kernel(const float* __restrict__ x, int* __restrict__ idx)
{
    const int bn = blockIdx.x;
    const int b = bn >> 11;
    const int n = bn & (NPTS - 1);
    const float* xb = x + b * 3 * NPTS;
    const float qx = xb[n], qy = xb[NPTS + n], qz = xb[2 * NPTS + n];
    const float sqn = fmaf(qz, qz, fmaf(qy, qy, qx * qx));
    const int t = threadIdx.x;
    unsigned long long best[8];
#pragma unroll
    for (int i = 0; i < 8; i++) {
        int m = t + (i << 8);
        float mx = xb[m], my = xb[NPTS + m], mz = xb[2 * NPTS + m];
        float sqm = fmaf(mz, mz, fmaf(my, my, mx * mx));
        float dt  = fmaf(qz, mz, fmaf(qy, my, qx * mx));
        float d2  = sqn + sqm - 2.0f * dt;
        unsigned u = __float_as_uint(d2);
        u ^= (u & 0x80000000u) ? 0xFFFFFFFFu : 0x80000000u;  // monotone map
        best[i] = ((unsigned long long)u << 32) | (unsigned)m;
    }
    __shared__ unsigned long long red[4];
    __shared__ unsigned long long winner;
    for (int r = 0; r < KNN_K; r++) {
        unsigned long long v = best[0];
#pragma unroll
        for (int i = 1; i < 8; i++) v = umin64(v, best[i]);
#pragma unroll
        for (int off = 32; off > 0; off >>= 1) {
            unsigned long long o = __shfl_down(v, off, 64);
            v = umin64(v, o);
        }
        if ((t & 63) == 0) red[t >> 6] = v;
        __syncthreads();
        if (t == 0) {
            unsigned long long w = umin64(umin64(red[0], red[1]), umin64(red[2], red[3]));
            winner = w;
            idx[bn * KNN_K + r] = (int)(w & 0xFFFFFFFFull);
        }
        __syncthreads();
        unsigned long long w = winner;
#pragma unroll
        for (int i = 0; i < 8; i++) if (best[i] == w) best[i] = ~0ull;
        __syncthreads();
    }
}

// ---------------------------------------------------------------------------
// Build stacked edge-layer weight [4*O, C]: rows g*O+o
//   g0: Wf[o, c]            (applies to neighbor term AF)
//   g1: Wf[o, C+c]-Wf[o,c]  (center term GF)
//   g2: Wd[o, c]            (AD)
//   g3: Wd[o, C+c]-Wd[o,c]  (GD)
// ---------------------------------------------------------------------------
__global__ void build_wbig(const float* __restrict__ Wf, const float* __restrict__ Wd,
                           float* __restrict__ out, int O, int C)
{
    int i = blockIdx.x * 256 + threadIdx.x;
    int total = 4 * O * C;
    if (i >= total) return;
    int c = i % C;
    int j = i / C;
    int g = j / O;
    int o = j % O;
    float v;
    if (g == 0)      v = Wf[o * 2 * C + c];
    else if (g == 1) v = Wf[o * 2 * C + C + c] - Wf[o * 2 * C + c];
    else if (g == 2) v = Wd[o * 2 * C + c];
    else             v = Wd[o * 2 * C + C + c] - Wd[o * 2 * C + c];
    out[i] = v;
}

// stack two weight matrices [Oa,K] and [Ob,K] into [Ot,K] (zero-pad rows)
__global__ void build_stack(const float* __restrict__ Wa, int Oa,
                            const float* __restrict__ Wb, int Ob, int K,
                            float* __restrict__ out, int Ot)
{
    int i = blockIdx.x * 256 + threadIdx.x;
    if (i >= Ot * K) return;
    int r = i / K;
    int c = i % K;
    float v = 0.f;
    if (r < Oa) v = Wa[r * K + c];
    else if (r < Oa + Ob) v = Wb[(r - Oa) * K + c];
    out[i] = v;
}

// ---------------------------------------------------------------------------
// GEMM (NT): OUT[m, o] = sum_k X[m, xoff+k] * W[o, k]
// X: MROWS rows, row stride ldx. W: [O, K] row-major. OUT row stride ldo.
// 64x64 tile, BK=16, 256 threads, 4x4 microtile.
// ---------------------------------------------------------------------------
__global__ __launch_bounds__(256) void gemm_nt(const float* __restrict__ X, int ldx, int xoff,
                                               const float* __restrict__ W,
                                               float* __restrict__ OUT, int ldo,
                                               int K, int O)
{
    __shared__ float Xs[16][68];
    __shared__ float Ws[16][68];
    const int tid = threadIdx.x;
    const int bm = blockIdx.x * 64;
    const int bo = blockIdx.y * 64;
    const int lr = tid >> 2;          // 0..63 row-in-tile for loads
    const int lk = (tid & 3) << 2;    // 0,4,8,12
    const int tm = (tid & 15) << 2;   // micro row (m)
    const int to = (tid >> 4) << 2;   // micro col (o)
    float acc[4][4] = {};

    for (int k0 = 0; k0 < K; k0 += 16) {
        float4 xv;
        {
            const float* xp = X + (size_t)(bm + lr) * ldx + xoff + k0 + lk;
            if (k0 + lk + 3 < K) {
                xv = *(const float4*)xp;
            } else {
                xv.x = (k0 + lk     < K) ? xp[0] : 0.f;
                xv.y = (k0 + lk + 1 < K) ? xp[1] : 0.f;
                xv.z = (k0 + lk + 2 < K) ? xp[2] : 0.f;
                xv.w = (k0 + lk + 3 < K) ? xp[3] : 0.f;
            }
        }
        float4 wv = make_float4(0.f, 0.f, 0.f, 0.f);
        {
            const int wr = bo + lr;
            if (wr < O) {
                const float* wp = W + (size_t)wr * K + k0 + lk;
                if (k0 + lk + 3 < K) {
                    wv = *(const float4*)wp;
                } else {
                    wv.x = (k0 + lk     < K) ? wp[0] : 0.f;
                    wv.y = (k0 + lk + 1 < K) ? wp[1] : 0.f;
                    wv.z = (k0 + lk + 2 < K) ? wp[2] : 0.f;
                    wv.w = (k0 + lk + 3 < K) ? wp[3] : 0.f;
                }
            }
        }
        Xs[lk + 0][lr] = xv.x; Xs[lk + 1][lr] = xv.y;
        Xs[lk + 2][lr] = xv.z; Xs[lk + 3][lr] = xv.w;
        Ws[lk + 0][lr] = wv.x; Ws[lk + 1][lr] = wv.y;
        Ws[lk + 2][lr] = wv.z; Ws[lk + 3][lr] = wv.w;
        __syncthreads();
#pragma unroll
        for (int kk = 0; kk < 16; kk++) {
            float4 a = *(const float4*)&Xs[kk][tm];
            float4 bv = *(const float4*)&Ws[kk][to];
            acc[0][0] = fmaf(a.x, bv.x, acc[0][0]);
            acc[0][1] = fmaf(a.x, bv.y, acc[0][1]);
            acc[0][2] = fmaf(a.x, bv.z, acc[0][2]);
            acc[0][3] = fmaf(a.x, bv.w, acc[0][3]);
            acc[1][0] = fmaf(a.y, bv.x, acc[1][0]);
            acc[1][1] = fmaf(a.y, bv.y, acc[1][1]);
            acc[1][2] = fmaf(a.y, bv.z, acc[1][2]);
            acc[1][3] = fmaf(a.y, bv.w, acc[1][3]);
            acc[2][0] = fmaf(a.z, bv.x, acc[2][0]);
            acc[2][1] = fmaf(a.z, bv.y, acc[2][1]);
            acc[2][2] = fmaf(a.z, bv.z, acc[2][2]);
            acc[2][3] = fmaf(a.z, bv.w, acc[2][3]);
            acc[3][0] = fmaf(a.w, bv.x, acc[3][0]);
            acc[3][1] = fmaf(a.w, bv.y, acc[3][1]);
            acc[3][2] = fmaf(a.w, bv.z, acc[3][2]);
            acc[3][3] = fmaf(a.w, bv.w, acc[3][3]);
        }
        __syncthreads();
    }

    const int oc = bo + to;
    if (oc < O) {
#pragma unroll
        for (int i = 0; i < 4; i++) {
            int orow = bm + tm + i;
            float4 r = make_float4(acc[i][0], acc[i][1], acc[i][2], acc[i][3]);
            *(float4*)&OUT[(size_t)orow * ldo + oc] = r;
        }
    }
}

// ---------------------------------------------------------------------------
// Edge conv + vec_lna + mean over K neighbors.
// AG: [MROWS, 4*O] = [AF | GF | AD | GD]; out[(gp*3+v)*ldo + ooff + o]
// ---------------------------------------------------------------------------
template <int O, int PT>
__global__ __launch_bounds__(256) void edge_kernel(const float* __restrict__ AG,
                                                   const int* __restrict__ idx,
                                                   float* __restrict__ out, int ldo, int ooff)
{
    const int tid = threadIdx.x;
    const int o = tid % O;
    const int pt = tid / O;
    const int gp = blockIdx.x * PT + pt;
    const int b = gp >> 11;
    __shared__ int sIdx[PT][KNN_K];
    if (tid < PT * KNN_K) {
        sIdx[tid >> 4][tid & 15] = idx[(blockIdx.x * PT + (tid >> 4)) * KNN_K + (tid & 15)];
    }
    __syncthreads();
    const int ld = 4 * O;
    const int rown = gp * 3;
    const float GF0 = AG[(rown + 0) * ld + O + o];
    const float GF1 = AG[(rown + 1) * ld + O + o];
    const float GF2 = AG[(rown + 2) * ld + O + o];
    const float GD0 = AG[(rown + 0) * ld + 3 * O + o];
    const float GD1 = AG[(rown + 1) * ld + 3 * O + o];
    const float GD2 = AG[(rown + 2) * ld + 3 * O + o];
    float a0 = 0.f, a1 = 0.f, a2 = 0.f;
    const int bbase = (b << 11) * 3;
#pragma unroll
    for (int k = 0; k < KNN_K; k++) {
        int m = sIdx[pt][k];
        const float* base = AG + (bbase + m * 3) * ld + o;
        float p0 = base[0]           + GF0;
        float d0 = base[2 * O]       + GD0;
        float p1 = base[ld]          + GF1;
        float d1 = base[ld + 2 * O]  + GD1;
        float p2 = base[2 * ld]          + GF2;
        float d2 = base[2 * ld + 2 * O]  + GD2;
        float dot = fmaf(p2, d2, fmaf(p1, d1, p0 * d0));
        float dsq = fmaf(d2, d2, fmaf(d1, d1, d0 * d0));
        float s = (dot < 0.f) ? 0.8f * dot / (dsq + 1e-6f) : 0.f;
        a0 += fmaf(-s, d0, p0);
        a1 += fmaf(-s, d1, p1);
        a2 += fmaf(-s, d2, p2);
    }
    out[(rown + 0) * ldo + ooff + o] = a0 * 0.0625f;
    out[(rown + 1) * ldo + ooff + o] = a1 * 0.0625f;
    out[(rown + 2) * ldo + ooff + o] = a2 * 0.0625f;
}

// ---------------------------------------------------------------------------
// vec_lna for wc: PD [MROWS,132] (p=cols 0..127, d=col 128, shared over o)
// -> xcat2 cols 0..127 (ld 256)
// ---------------------------------------------------------------------------
__global__ __launch_bounds__(256) void lna_wc_kernel(const float* __restrict__ PD, float* __restrict__ out)
{
    const int tid = threadIdx.x;
    const int o = tid & 127;
    const int pt = tid >> 7;
    const int gp = blockIdx.x * 2 + pt;
    const int row = gp * 3;
    const float d0 = PD[(row + 0) * 132 + 128];
    const float d1 = PD[(row + 1) * 132 + 128];
    const float d2 = PD[(row + 2) * 132 + 128];
    const float dsq = fmaf(d2, d2, fmaf(d1, d1, d0 * d0));
    const float p0 = PD[(row + 0) * 132 + o];
    const float p1 = PD[(row + 1) * 132 + o];
    const float p2 = PD[(row + 2) * 132 + o];
    const float dot = fmaf(p2, d2, fmaf(p1, d1, p0 * d0));
    const float s = (dot < 0.f) ? 0.8f * dot / (dsq + 1e-6f) : 0.f;
    out[(row + 0) * 256 + o] = fmaf(-s, d0, p0);
    out[(row + 1) * 256 + o] = fmaf(-s, d1, p1);
    out[(row + 2) * 256 + o] = fmaf(-s, d2, p2);
}

// vec_lna generic per-o d: PD [MROWS, 2*OC] (p=0..OC-1, d=OC..2OC-1) -> out ld OC
__global__ __launch_bounds__(256) void lna_128_kernel(const float* __restrict__ PD, float* __restrict__ out)
{
    const int tid = threadIdx.x;
    const int o = tid & 127;
    const int pt = tid >> 7;
    const int gp = blockIdx.x * 2 + pt;
    const int row = gp * 3;
    float p[3], d[3];
#pragma unroll
    for (int v = 0; v < 3; v++) {
        p[v] = PD[(row + v) * 256 + o];
        d[v] = PD[(row + v) * 256 + 128 + o];
    }
    float dot = fmaf(p[2], d[2], fmaf(p[1], d[1], p[0] * d[0]));
    float dsq = fmaf(d[2], d[2], fmaf(d[1], d[1], d[0] * d[0]));
    float s = (dot < 0.f) ? 0.8f * dot / (dsq + 1e-6f) : 0.f;
#pragma unroll
    for (int v = 0; v < 3; v++) {
        out[(row + v) * 128 + o] = fmaf(-s, d[v], p[v]);
    }
}

// ---------------------------------------------------------------------------
// xm = mean over n of xcat2 cols 0..127, then broadcast into cols 128..255
// ---------------------------------------------------------------------------
__global__ void xm_partial_kernel(const float* __restrict__ xcat2, float* __restrict__ part)
{
    const int g = blockIdx.x;        // B*3*32 = 384
    const int s = g & 31;
    const int bv = g >> 5;           // 0..11  (b*3+v)
    const int b = bv / 3;
    const int v = bv % 3;
    const int o = threadIdx.x;       // 128
    float acc = 0.f;
    for (int i = 0; i < 64; i++) {
        int n = s * 64 + i;
        acc += xcat2[((b * NPTS + n) * 3 + v) * 256 + o];
    }
    part[(bv * 32 + s) * 128 + o] = acc;
}

__global__ void xm_final_kernel(const float* __restrict__ part, float* __restrict__ xm)
{
    const int bv = blockIdx.x;       // 12
    const int o = threadIdx.x;       // 128
    float acc = 0.f;
    for (int i = 0; i < 32; i++) acc += part[(bv * 32 + i) * 128 + o];
    xm[bv * 128 + o] = acc * (1.f / 2048.f);
}

__global__ void xm_bcast_kernel(const float* __restrict__ xm, float* __restrict__ xcat2)
{
    int i = blockIdx.x * 256 + threadIdx.x;   // MROWS*128
    int row = i >> 7;
    int o = i & 127;
    int b = row / (3 * NPTS);
    int v = row % 3;
    xcat2[row * 256 + 128 + o] = xm[(b * 3 + v) * 128 + o];
}

// ---------------------------------------------------------------------------
// final: vec_lna(wi2 PD) fused with inv = sum_v xcat2 * x0, LDS transpose to
// output layout (B, 256, N)
// ---------------------------------------------------------------------------
__global__ __launch_bounds__(256) void final_inv_kernel(const float* __restrict__ PD2,
                                                        const float* __restrict__ xcat2,
                                                        float* __restrict__ out)
{
    __shared__ float sh[32][257];
    const int tid = threadIdx.x;     // o = tid, 0..255
    const int base_gp = blockIdx.x * 32;
    const int b = base_gp >> 11;
    const int n0 = base_gp & (NPTS - 1);
    for (int pt = 0; pt < 32; pt++) {
        const int row = (base_gp + pt) * 3;
        float p[3], d[3], xc[3];
#pragma unroll
        for (int v = 0; v < 3; v++) {
            p[v]  = PD2[(size_t)(row + v) * 512 + tid];
            d[v]  = PD2[(size_t)(row + v) * 512 + 256 + tid];
            xc[v] = xcat2[(row + v) * 256 + tid];
        }
        float dot = fmaf(p[2], d[2], fmaf(p[1], d[1], p[0] * d[0]));
        float dsq = fmaf(d[2], d[2], fmaf(d[1], d[1], d[0] * d[0]));
        float s = (dot < 0.f) ? 0.8f * dot / (dsq + 1e-6f) : 0.f;
        float inv = 0.f;
#pragma unroll
        for (int v = 0; v < 3; v++) {
            inv = fmaf(xc[v], fmaf(-s, d[v], p[v]), inv);
        }
        sh[pt][tid] = inv;
    }
    __syncthreads();
#pragma unroll
    for (int j = 0; j < 32; j++) {
        int ow = (tid >> 5) + j * 8;
        int pt2 = tid & 31;
        out[((size_t)b * 256 + ow) * NPTS + n0 + pt2] = sh[pt2][ow];
    }
}

// ---------------------------------------------------------------------------
// launch
// ---------------------------------------------------------------------------
extern "C" void kernel_launch(void* const* d_in, const int* in_sizes, int n_in,
                              void* d_out, int out_size, void* d_ws, size_t ws_size,
                              hipStream_t stream)
{
    const float* x    = (const float*)d_in[0];
    const float* w1f  = (const float*)d_in[1];
    const float* w1d  = (const float*)d_in[2];
    const float* w2f  = (const float*)d_in[3];
    const float* w2d  = (const float*)d_in[4];
    const float* w3f  = (const float*)d_in[5];
    const float* w3d  = (const float*)d_in[6];
    const float* w4f  = (const float*)d_in[7];
    const float* w4d  = (const float*)d_in[8];
    const float* wcf  = (const float*)d_in[9];
    const float* wcd  = (const float*)d_in[10];
    const float* wi1f = (const float*)d_in[11];
    const float* wi1d = (const float*)d_in[12];
    const float* wi2f = (const float*)d_in[13];
    const float* wi2d = (const float*)d_in[14];
    float* out = (float*)d_out;

    float* F = (float*)d_ws;
    size_t off = 0;
    float* AG      = F + off; off += (size_t)MROWS * 512;   // 12.58M, reused as PD buffers
    float* xcat240 = F + off; off += (size_t)MROWS * 240;   // x1..x4 (also reused as y1)
    float* xcat2   = F + off; off += (size_t)MROWS * 256;   // [xc | xm]
    float* x0cm    = F + off; off += MROWS;
    float* Wb1     = F + off; off += 64;
    float* Wb2     = F + off; off += 2048;
    float* Wb3     = F + off; off += 8192;
    float* Wb4     = F + off; off += 32768;
    float* Wc      = F + off; off += 132 * 240;
    float* Wi1     = F + off; off += 256 * 256;
    float* Wi2     = F + off; off += 512 * 128;
    float* part    = F + off; off += 12 * 32 * 128;
    float* xm      = F + off; off += 12 * 128;
    int* idx       = (int*)(F + off);
    float* y1 = xcat240;   // alias: xcat240 dead after wc GEMM

    // prep
    xpose_kernel<<<MROWS / 256, 256, 0, stream>>>(x, x0cm);
    knn_kernel<<<NBP, 256, 0, stream>>>(x, idx);
    build_wbig<<<1, 256, 0, stream>>>(w1f, w1d, Wb1, 16, 1);
    build_wbig<<<8, 256, 0, stream>>>(w2f, w2d, Wb2, 32, 16);
    build_wbig<<<32, 256, 0, stream>>>(w3f, w3d, Wb3, 64, 32);
    build_wbig<<<128, 256, 0, stream>>>(w4f, w4d, Wb4, 128, 64);
    build_stack<<<(132 * 240 + 255) / 256, 256, 0, stream>>>(wcf, 128, wcd, 1, 240, Wc, 132);
    build_stack<<<256, 256, 0, stream>>>(wi1f, 128, wi1d, 128, 256, Wi1, 256);
    build_stack<<<256, 256, 0, stream>>>(wi2f, 256, wi2d, 256, 128, Wi2, 512);

    const int GM = MROWS / 64;   // 384

    // layer 1: C=1, O=16
    gemm_nt<<<dim3(GM, 1), 256, 0, stream>>>(x0cm, 1, 0, Wb1, AG, 64, 1, 64);
    edge_kernel<16, 16><<<NBP / 16, 256, 0, stream>>>(AG, idx, xcat240, 240, 0);
    // layer 2: C=16, O=32
    gemm_nt<<<dim3(GM, 2), 256, 0, stream>>>(xcat240, 240, 0, Wb2, AG, 128, 16, 128);
    edge_kernel<32, 8><<<NBP / 8, 256, 0, stream>>>(AG, idx, xcat240, 240, 16);
    // layer 3: C=32, O=64
    gemm_nt<<<dim3(GM, 4), 256, 0, stream>>>(xcat240, 240, 16, Wb3, AG, 256, 32, 256);
    edge_kernel<64, 4><<<NBP / 4, 256, 0, stream>>>(AG, idx, xcat240, 240, 48);
    // layer 4: C=64, O=128
    gemm_nt<<<dim3(GM, 8), 256, 0, stream>>>(xcat240, 240, 48, Wb4, AG, 512, 64, 512);
    edge_kernel<128, 2><<<NBP / 2, 256, 0, stream>>>(AG, idx, xcat240, 240, 112);

    // wc: K=240 -> PD [MROWS,132]
    gemm_nt<<<dim3(GM, 3), 256, 0, stream>>>(xcat240, 240, 0, Wc, AG, 132, 240, 132);
    lna_wc_kernel<<<NBP / 2, 256, 0, stream>>>(AG, xcat2);

    // xm mean + broadcast
    xm_partial_kernel<<<BATCH * 3 * 32, 128, 0, stream>>>(xcat2, part);
    xm_final_kernel<<<BATCH * 3, 128, 0, stream>>>(part, xm);
    xm_bcast_kernel<<<(MROWS * 128) / 256, 256, 0, stream>>>(xm, xcat2);

    // wi1: K=256 -> PD [MROWS,256] -> y1 [MROWS,128]
    gemm_nt<<<dim3(GM, 4), 256, 0, stream>>>(xcat2, 256, 0, Wi1, AG, 256, 256, 256);
    lna_128_kernel<<<NBP / 2, 256, 0, stream>>>(AG, y1);

    // wi2: K=128 -> PD [MROWS,512] -> fused lna + inv + transpose
    gemm_nt<<<dim3(GM, 8), 256, 0, stream>>>(y1, 128, 0, Wi2, AG, 512, 128, 512);
    final_inv_kernel<<<NBP / 32, 256, 0, stream>>>(AG, xcat2, out);

    (void)in_sizes; (void)n_in; (void)out_size; (void)ws_size;
}

// Round 2
// 470.903 us; speedup vs baseline: 1.0509x; 1.0509x over previous
//
#include <hip/hip_runtime.h>

#define NPTS  2048
#define BATCH 4
#define NBP   8192      // BATCH*NPTS
#define MROWS 24576     // NBP*3
#define KNN_K 16

// ---------------------------------------------------------------------------
// transpose input x (B,3,N) -> x0cm[(b*N+n)*3+v]
// ---------------------------------------------------------------------------
__global__ void xpose_kernel(const float* __restrict__ x, float* __restrict__ x0cm)
{
    int i = blockIdx.x * 256 + threadIdx.x;   // over MROWS
    if (i >= MROWS) return;
    int v = i % 3;
    int bn = i / 3;
    int b = bn >> 11;
    int n = bn & (NPTS - 1);
    x0cm[i] = x[(b * 3 + v) * NPTS + n];
}

// ---------------------------------------------------------------------------
// KNN: one WAVE per query (4 queries / 256-block, no __syncthreads, no LDS).
// Lane t holds 32 candidates m = (i<<6)|t as u32 monotone-float keys.
// 16 rounds: butterfly wave-min of cached lane-min; tied lanes propose
// m=(i_min<<6)|t; second butterfly min picks lowest global index (= top_k
// stable tie-break); single owner lane zaps its slot + refreshes lane-min.
// ---------------------------------------------------------------------------
__global__ __launch_bounds__(256) void knn_kernel(const float* __restrict__ x, int* __restrict__ idx)
{
    const int wave = threadIdx.x >> 6;
    const int t    = threadIdx.x & 63;
    const int bn   = blockIdx.x * 4 + wave;   // query id
    const int b = bn >> 11;
    const int n = bn & (NPTS - 1);
    const float* xb = x + b * 3 * NPTS;
    const float qx = xb[n], qy = xb[NPTS + n], qz = xb[2 * NPTS + n];
    const float sqn = fmaf(qz, qz, fmaf(qy, qy, qx * qx));

    unsigned key[32];
#pragma unroll
    for (int i = 0; i < 32; i++) {
        int m = (i << 6) + t;
        float mx = xb[m], my = xb[NPTS + m], mz = xb[2 * NPTS + m];
        float sqm = fmaf(mz, mz, fmaf(my, my, mx * mx));
        float dt  = fmaf(qz, mz, fmaf(qy, my, qx * mx));
        float d2  = sqn + sqm - 2.0f * dt;
        unsigned u = __float_as_uint(d2);
        u ^= (u & 0x80000000u) ? 0xFFFFFFFFu : 0x80000000u;  // monotone map
        key[i] = u;
    }
    unsigned lm = key[0];
#pragma unroll
    for (int i = 1; i < 32; i++) lm = min(lm, key[i]);

    int res = -1;
    for (int r = 0; r < KNN_K; r++) {
        unsigned wmin = lm;
#pragma unroll
        for (int off = 32; off > 0; off >>= 1)
            wmin = min(wmin, (unsigned)__shfl_xor((int)wmin, off, 64));

        unsigned cand = 0xFFFFFFFFu;
        int imin = 0;
        if (lm == wmin) {
            imin = 32;
#pragma unroll
            for (int i = 31; i >= 0; i--) if (key[i] == wmin) imin = i;
            cand = (unsigned)((imin << 6) | t);
        }
        unsigned mwin = cand;
#pragma unroll
        for (int off = 32; off > 0; off >>= 1)
            mwin = min(mwin, (unsigned)__shfl_xor((int)mwin, off, 64));

        if (cand == mwin) {            // exactly one owner lane
#pragma unroll
            for (int i = 0; i < 32; i++) if (i == imin) key[i] = 0xFFFFFFFFu;
            lm = key[0];
#pragma unroll
            for (int i = 1; i < 32; i++) lm = min(lm, key[i]);
        }
        if (t == r) res = (int)mwin;
    }
    if (t < KNN_K) idx[bn * KNN_K + t] = res;
}

// ---------------------------------------------------------------------------
// Build stacked edge-layer weight [4*O, C]: rows g*O+o
//   g0: Wf[o, c]            (applies to neighbor term AF)
//   g1: Wf[o, C+c]-Wf[o,c]  (center term GF)
//   g2: Wd[o, c]            (AD)
//   g3: Wd[o, C+c]-Wd[o,c]  (GD)
// ---------------------------------------------------------------------------
__global__ void build_wbig(const float* __restrict__ Wf, const float* __restrict__ Wd,
                           float* __restrict__ out, int O, int C)
{
    int i = blockIdx.x * 256 + threadIdx.x;
    int total = 4 * O * C;
    if (i >= total) return;
    int c = i % C;
    int j = i / C;
    int g = j / O;
    int o = j % O;
    float v;
    if (g == 0)      v = Wf[o * 2 * C + c];
    else if (g == 1) v = Wf[o * 2 * C + C + c] - Wf[o * 2 * C + c];
    else if (g == 2) v = Wd[o * 2 * C + c];
    else             v = Wd[o * 2 * C + C + c] - Wd[o * 2 * C + c];
    out[i] = v;
}

// stack two weight matrices [Oa,K] and [Ob,K] into [Ot,K] (zero-pad rows)
__global__ void build_stack(const float* __restrict__ Wa, int Oa,
                            const float* __restrict__ Wb, int Ob, int K,
                            float* __restrict__ out, int Ot)
{
    int i = blockIdx.x * 256 + threadIdx.x;
    if (i >= Ot * K) return;
    int r = i / K;
    int c = i % K;
    float v = 0.f;
    if (r < Oa) v = Wa[r * K + c];
    else if (r < Oa + Ob) v = Wb[(r - Oa) * K + c];
    out[i] = v;
}

// ---------------------------------------------------------------------------
// GEMM (NT): OUT[m, o] = sum_k X[m, xoff+k] * W[o, k]
// X: MROWS rows, row stride ldx. W: [O, K] row-major. OUT row stride ldo.
// 64x64 tile, BK=16, 256 threads, 4x4 microtile.
// ---------------------------------------------------------------------------
__global__ __launch_bounds__(256) void gemm_nt(const float* __restrict__ X, int ldx, int xoff,
                                               const float* __restrict__ W,
                                               float* __restrict__ OUT, int ldo,
                                               int K, int O)
{
    __shared__ float Xs[16][68];
    __shared__ float Ws[16][68];
    const int tid = threadIdx.x;
    const int bm = blockIdx.x * 64;
    const int bo = blockIdx.y * 64;
    const int lr = tid >> 2;          // 0..63 row-in-tile for loads
    const int lk = (tid & 3) << 2;    // 0,4,8,12
    const int tm = (tid & 15) << 2;   // micro row (m)
    const int to = (tid >> 4) << 2;   // micro col (o)
    float acc[4][4] = {};

    for (int k0 = 0; k0 < K; k0 += 16) {
        float4 xv;
        {
            const float* xp = X + (size_t)(bm + lr) * ldx + xoff + k0 + lk;
            if (k0 + lk + 3 < K) {
                xv = *(const float4*)xp;
            } else {
                xv.x = (k0 + lk     < K) ? xp[0] : 0.f;
                xv.y = (k0 + lk + 1 < K) ? xp[1] : 0.f;
                xv.z = (k0 + lk + 2 < K) ? xp[2] : 0.f;
                xv.w = (k0 + lk + 3 < K) ? xp[3] : 0.f;
            }
        }
        float4 wv = make_float4(0.f, 0.f, 0.f, 0.f);
        {
            const int wr = bo + lr;
            if (wr < O) {
                const float* wp = W + (size_t)wr * K + k0 + lk;
                if (k0 + lk + 3 < K) {
                    wv = *(const float4*)wp;
                } else {
                    wv.x = (k0 + lk     < K) ? wp[0] : 0.f;
                    wv.y = (k0 + lk + 1 < K) ? wp[1] : 0.f;
                    wv.z = (k0 + lk + 2 < K) ? wp[2] : 0.f;
                    wv.w = (k0 + lk + 3 < K) ? wp[3] : 0.f;
                }
            }
        }
        Xs[lk + 0][lr] = xv.x; Xs[lk + 1][lr] = xv.y;
        Xs[lk + 2][lr] = xv.z; Xs[lk + 3][lr] = xv.w;
        Ws[lk + 0][lr] = wv.x; Ws[lk + 1][lr] = wv.y;
        Ws[lk + 2][lr] = wv.z; Ws[lk + 3][lr] = wv.w;
        __syncthreads();
#pragma unroll
        for (int kk = 0; kk < 16; kk++) {
            float4 a = *(const float4*)&Xs[kk][tm];
            float4 bv = *(const float4*)&Ws[kk][to];
            acc[0][0] = fmaf(a.x, bv.x, acc[0][0]);
            acc[0][1] = fmaf(a.x, bv.y, acc[0][1]);
            acc[0][2] = fmaf(a.x, bv.z, acc[0][2]);
            acc[0][3] = fmaf(a.x, bv.w, acc[0][3]);
            acc[1][0] = fmaf(a.y, bv.x, acc[1][0]);
            acc[1][1] = fmaf(a.y, bv.y, acc[1][1]);
            acc[1][2] = fmaf(a.y, bv.z, acc[1][2]);
            acc[1][3] = fmaf(a.y, bv.w, acc[1][3]);
            acc[2][0] = fmaf(a.z, bv.x, acc[2][0]);
            acc[2][1] = fmaf(a.z, bv.y, acc[2][1]);
            acc[2][2] = fmaf(a.z, bv.z, acc[2][2]);
            acc[2][3] = fmaf(a.z, bv.w, acc[2][3]);
            acc[3][0] = fmaf(a.w, bv.x, acc[3][0]);
            acc[3][1] = fmaf(a.w, bv.y, acc[3][1]);
            acc[3][2] = fmaf(a.w, bv.z, acc[3][2]);
            acc[3][3] = fmaf(a.w, bv.w, acc[3][3]);
        }
        __syncthreads();
    }

    const int oc = bo + to;
    if (oc < O) {
#pragma unroll
        for (int i = 0; i < 4; i++) {
            int orow = bm + tm + i;
            float4 r = make_float4(acc[i][0], acc[i][1], acc[i][2], acc[i][3]);
            *(float4*)&OUT[(size_t)orow * ldo + oc] = r;
        }
    }
}

// ---------------------------------------------------------------------------
// Edge conv + vec_lna + mean over K neighbors.
// AG: [MROWS, 4*O] = [AF | GF | AD | GD]; out[(gp*3+v)*ldo + ooff + o]
// ---------------------------------------------------------------------------
template <int O, int PT>
__global__ __launch_bounds__(256) void edge_kernel(const float* __restrict__ AG,
                                                   const int* __restrict__ idx,
                                                   float* __restrict__ out, int ldo, int ooff)
{
    const int tid = threadIdx.x;
    const int o = tid % O;
    const int pt = tid / O;
    const int gp = blockIdx.x * PT + pt;
    const int b = gp >> 11;
    __shared__ int sIdx[PT][KNN_K];
    if (tid < PT * KNN_K) {
        sIdx[tid >> 4][tid & 15] = idx[(blockIdx.x * PT + (tid >> 4)) * KNN_K + (tid & 15)];
    }
    __syncthreads();
    const int ld = 4 * O;
    const int rown = gp * 3;
    const float GF0 = AG[(rown + 0) * ld + O + o];
    const float GF1 = AG[(rown + 1) * ld + O + o];
    const float GF2 = AG[(rown + 2) * ld + O + o];
    const float GD0 = AG[(rown + 0) * ld + 3 * O + o];
    const float GD1 = AG[(rown + 1) * ld + 3 * O + o];
    const float GD2 = AG[(rown + 2) * ld + 3 * O + o];
    float a0 = 0.f, a1 = 0.f, a2 = 0.f;
    const int bbase = (b << 11) * 3;
#pragma unroll
    for (int k = 0; k < KNN_K; k++) {
        int m = sIdx[pt][k];
        const float* base = AG + (bbase + m * 3) * ld + o;
        float p0 = base[0]           + GF0;
        float d0 = base[2 * O]       + GD0;
        float p1 = base[ld]          + GF1;
        float d1 = base[ld + 2 * O]  + GD1;
        float p2 = base[2 * ld]          + GF2;
        float d2 = base[2 * ld + 2 * O]  + GD2;
        float dot = fmaf(p2, d2, fmaf(p1, d1, p0 * d0));
        float dsq = fmaf(d2, d2, fmaf(d1, d1, d0 * d0));
        float s = (dot < 0.f) ? 0.8f * dot / (dsq + 1e-6f) : 0.f;
        a0 += fmaf(-s, d0, p0);
        a1 += fmaf(-s, d1, p1);
        a2 += fmaf(-s, d2, p2);
    }
    out[(rown + 0) * ldo + ooff + o] = a0 * 0.0625f;
    out[(rown + 1) * ldo + ooff + o] = a1 * 0.0625f;
    out[(rown + 2) * ldo + ooff + o] = a2 * 0.0625f;
}

// ---------------------------------------------------------------------------
// vec_lna for wc: PD [MROWS,132] (p=cols 0..127, d=col 128, shared over o)
// -> xcat2 cols 0..127 (ld 256)
// ---------------------------------------------------------------------------
__global__ __launch_bounds__(256) void lna_wc_kernel(const float* __restrict__ PD, float* __restrict__ out)
{
    const int tid = threadIdx.x;
    const int o = tid & 127;
    const int pt = tid >> 7;
    const int gp = blockIdx.x * 2 + pt;
    const int row = gp * 3;
    const float d0 = PD[(row + 0) * 132 + 128];
    const float d1 = PD[(row + 1) * 132 + 128];
    const float d2 = PD[(row + 2) * 132 + 128];
    const float dsq = fmaf(d2, d2, fmaf(d1, d1, d0 * d0));
    const float p0 = PD[(row + 0) * 132 + o];
    const float p1 = PD[(row + 1) * 132 + o];
    const float p2 = PD[(row + 2) * 132 + o];
    const float dot = fmaf(p2, d2, fmaf(p1, d1, p0 * d0));
    const float s = (dot < 0.f) ? 0.8f * dot / (dsq + 1e-6f) : 0.f;
    out[(row + 0) * 256 + o] = fmaf(-s, d0, p0);
    out[(row + 1) * 256 + o] = fmaf(-s, d1, p1);
    out[(row + 2) * 256 + o] = fmaf(-s, d2, p2);
}

// vec_lna generic per-o d: PD [MROWS, 2*OC] (p=0..OC-1, d=OC..2OC-1) -> out ld OC
__global__ __launch_bounds__(256) void lna_128_kernel(const float* __restrict__ PD, float* __restrict__ out)
{
    const int tid = threadIdx.x;
    const int o = tid & 127;
    const int pt = tid >> 7;
    const int gp = blockIdx.x * 2 + pt;
    const int row = gp * 3;
    float p[3], d[3];
#pragma unroll
    for (int v = 0; v < 3; v++) {
        p[v] = PD[(row + v) * 256 + o];
        d[v] = PD[(row + v) * 256 + 128 + o];
    }
    float dot = fmaf(p[2], d[2], fmaf(p[1], d[1], p[0] * d[0]));
    float dsq = fmaf(d[2], d[2], fmaf(d[1], d[1], d[0] * d[0]));
    float s = (dot < 0.f) ? 0.8f * dot / (dsq + 1e-6f) : 0.f;
#pragma unroll
    for (int v = 0; v < 3; v++) {
        out[(row + v) * 128 + o] = fmaf(-s, d[v], p[v]);
    }
}

// ---------------------------------------------------------------------------
// xm = mean over n of xcat2 cols 0..127, then broadcast into cols 128..255
// ---------------------------------------------------------------------------
__global__ void xm_partial_kernel(const float* __restrict__ xcat2, float* __restrict__ part)
{
    const int g = blockIdx.x;        // B*3*32 = 384
    const int s = g & 31;
    const int bv = g >> 5;           // 0..11  (b*3+v)
    const int b = bv / 3;
    const int v = bv % 3;
    const int o = threadIdx.x;       // 128
    float acc = 0.f;
    for (int i = 0; i < 64; i++) {
        int n = s * 64 + i;
        acc += xcat2[((b * NPTS + n) * 3 + v) * 256 + o];
    }
    part[(bv * 32 + s) * 128 + o] = acc;
}

__global__ void xm_final_kernel(const float* __restrict__ part, float* __restrict__ xm)
{
    const int bv = blockIdx.x;       // 12
    const int o = threadIdx.x;       // 128
    float acc = 0.f;
    for (int i = 0; i < 32; i++) acc += part[(bv * 32 + i) * 128 + o];
    xm[bv * 128 + o] = acc * (1.f / 2048.f);
}

__global__ void xm_bcast_kernel(const float* __restrict__ xm, float* __restrict__ xcat2)
{
    int i = blockIdx.x * 256 + threadIdx.x;   // MROWS*128
    int row = i >> 7;
    int o = i & 127;
    int b = row / (3 * NPTS);
    int v = row % 3;
    xcat2[row * 256 + 128 + o] = xm[(b * 3 + v) * 128 + o];
}

// ---------------------------------------------------------------------------
// final: vec_lna(wi2 PD) fused with inv = sum_v xcat2 * x0, LDS transpose to
// output layout (B, 256, N)
// ---------------------------------------------------------------------------
__global__ __launch_bounds__(256) void final_inv_kernel(const float* __restrict__ PD2,
                                                        const float* __restrict__ xcat2,
                                                        float* __restrict__ out)
{
    __shared__ float sh[32][257];
    const int tid = threadIdx.x;     // o = tid, 0..255
    const int base_gp = blockIdx.x * 32;
    const int b = base_gp >> 11;
    const int n0 = base_gp & (NPTS - 1);
    for (int pt = 0; pt < 32; pt++) {
        const int row = (base_gp + pt) * 3;
        float p[3], d[3], xc[3];
#pragma unroll
        for (int v = 0; v < 3; v++) {
            p[v]  = PD2[(size_t)(row + v) * 512 + tid];
            d[v]  = PD2[(size_t)(row + v) * 512 + 256 + tid];
            xc[v] = xcat2[(row + v) * 256 + tid];
        }
        float dot = fmaf(p[2], d[2], fmaf(p[1], d[1], p[0] * d[0]));
        float dsq = fmaf(d[2], d[2], fmaf(d[1], d[1], d[0] * d[0]));
        float s = (dot < 0.f) ? 0.8f * dot / (dsq + 1e-6f) : 0.f;
        float inv = 0.f;
#pragma unroll
        for (int v = 0; v < 3; v++) {
            inv = fmaf(xc[v], fmaf(-s, d[v], p[v]), inv);
        }
        sh[pt][tid] = inv;
    }
    __syncthreads();
#pragma unroll
    for (int j = 0; j < 32; j++) {
        int ow = (tid >> 5) + j * 8;
        int pt2 = tid & 31;
        out[((size_t)b * 256 + ow) * NPTS + n0 + pt2] = sh[pt2][ow];
    }
}

// ---------------------------------------------------------------------------
// launch
// ---------------------------------------------------------------------------
extern "C" void kernel_launch(void* const* d_in, const int* in_sizes, int n_in,
                              void* d_out, int out_size, void* d_ws, size_t ws_size,
                              hipStream_t stream)
{
    const float* x    = (const float*)d_in[0];
    const float* w1f  = (const float*)d_in[1];
    const float* w1d  = (const float*)d_in[2];
    const float* w2f  = (const float*)d_in[3];
    const float* w2d  = (const float*)d_in[4];
    const float* w3f  = (const float*)d_in[5];
    const float* w3d  = (const float*)d_in[6];
    const float* w4f  = (const float*)d_in[7];
    const float* w4d  = (const float*)d_in[8];
    const float* wcf  = (const float*)d_in[9];
    const float* wcd  = (const float*)d_in[10];
    const float* wi1f = (const float*)d_in[11];
    const float* wi1d = (const float*)d_in[12];
    const float* wi2f = (const float*)d_in[13];
    const float* wi2d = (const float*)d_in[14];
    float* out = (float*)d_out;

    float* F = (float*)d_ws;
    size_t off = 0;
    float* AG      = F + off; off += (size_t)MROWS * 512;   // 12.58M, reused as PD buffers
    float* xcat240 = F + off; off += (size_t)MROWS * 240;   // x1..x4 (also reused as y1)
    float* xcat2   = F + off; off += (size_t)MROWS * 256;   // [xc | xm]
    float* x0cm    = F + off; off += MROWS;
    float* Wb1     = F + off; off += 64;
    float* Wb2     = F + off; off += 2048;
    float* Wb3     = F + off; off += 8192;
    float* Wb4     = F + off; off += 32768;
    float* Wc      = F + off; off += 132 * 240;
    float* Wi1     = F + off; off += 256 * 256;
    float* Wi2     = F + off; off += 512 * 128;
    float* part    = F + off; off += 12 * 32 * 128;
    float* xm      = F + off; off += 12 * 128;
    int* idx       = (int*)(F + off);
    float* y1 = xcat240;   // alias: xcat240 dead after wc GEMM

    // prep
    xpose_kernel<<<MROWS / 256, 256, 0, stream>>>(x, x0cm);
    knn_kernel<<<NBP / 4, 256, 0, stream>>>(x, idx);
    build_wbig<<<1, 256, 0, stream>>>(w1f, w1d, Wb1, 16, 1);
    build_wbig<<<8, 256, 0, stream>>>(w2f, w2d, Wb2, 32, 16);
    build_wbig<<<32, 256, 0, stream>>>(w3f, w3d, Wb3, 64, 32);
    build_wbig<<<128, 256, 0, stream>>>(w4f, w4d, Wb4, 128, 64);
    build_stack<<<(132 * 240 + 255) / 256, 256, 0, stream>>>(wcf, 128, wcd, 1, 240, Wc, 132);
    build_stack<<<256, 256, 0, stream>>>(wi1f, 128, wi1d, 128, 256, Wi1, 256);
    build_stack<<<256, 256, 0, stream>>>(wi2f, 256, wi2d, 256, 128, Wi2, 512);

    const int GM = MROWS / 64;   // 384

    // layer 1: C=1, O=16
    gemm_nt<<<dim3(GM, 1), 256, 0, stream>>>(x0cm, 1, 0, Wb1, AG, 64, 1, 64);
    edge_kernel<16, 16><<<NBP / 16, 256, 0, stream>>>(AG, idx, xcat240, 240, 0);
    // layer 2: C=16, O=32
    gemm_nt<<<dim3(GM, 2), 256, 0, stream>>>(xcat240, 240, 0, Wb2, AG, 128, 16, 128);
    edge_kernel<32, 8><<<NBP / 8, 256, 0, stream>>>(AG, idx, xcat240, 240, 16);
    // layer 3: C=32, O=64
    gemm_nt<<<dim3(GM, 4), 256, 0, stream>>>(xcat240, 240, 16, Wb3, AG, 256, 32, 256);
    edge_kernel<64, 4><<<NBP / 4, 256, 0, stream>>>(AG, idx, xcat240, 240, 48);
    // layer 4: C=64, O=128
    gemm_nt<<<dim3(GM, 8), 256, 0, stream>>>(xcat240, 240, 48, Wb4, AG, 512, 64, 512);
    edge_kernel<128, 2><<<NBP / 2, 256, 0, stream>>>(AG, idx, xcat240, 240, 112);

    // wc: K=240 -> PD [MROWS,132]
    gemm_nt<<<dim3(GM, 3), 256, 0, stream>>>(xcat240, 240, 0, Wc, AG, 132, 240, 132);
    lna_wc_kernel<<<NBP / 2, 256, 0, stream>>>(AG, xcat2);

    // xm mean + broadcast
    xm_partial_kernel<<<BATCH * 3 * 32, 128, 0, stream>>>(xcat2, part);
    xm_final_kernel<<<BATCH * 3, 128, 0, stream>>>(part, xm);
    xm_bcast_kernel<<<(MROWS * 128) / 256, 256, 0, stream>>>(xm, xcat2);

    // wi1: K=256 -> PD [MROWS,256] -> y1 [MROWS,128]
    gemm_nt<<<dim3(GM, 4), 256, 0, stream>>>(xcat2, 256, 0, Wi1, AG, 256, 256, 256);
    lna_128_kernel<<<NBP / 2, 256, 0, stream>>>(AG, y1);

    // wi2: K=128 -> PD [MROWS,512] -> fused lna + inv + transpose
    gemm_nt<<<dim3(GM, 8), 256, 0, stream>>>(y1, 128, 0, Wi2, AG, 512, 128, 512);
    final_inv_kernel<<<NBP / 32, 256, 0, stream>>>(AG, xcat2, out);

    (void)in_sizes; (void)n_in; (void)out_size; (void)ws_size;
}

// Round 3
// 391.842 us; speedup vs baseline: 1.2629x; 1.2018x over previous
//
#include <hip/hip_runtime.h>

#define NPTS  2048
#define BATCH 4
#define NBP   8192      // BATCH*NPTS
#define MROWS 24576     // NBP*3
#define KNN_K 16

typedef short bf16x8 __attribute__((ext_vector_type(8)));
typedef float f32x4  __attribute__((ext_vector_type(4)));

// split fp32 into bf16 hi + bf16 lo (RTNE), x ~= hi + lo to ~2^-17 rel
static __device__ __forceinline__ void split_bf16(float a, unsigned short& h, unsigned short& l)
{
    unsigned u = __float_as_uint(a);
    unsigned hr = (u + 0x7FFFu + ((u >> 16) & 1u)) & 0xFFFF0000u;
    h = (unsigned short)(hr >> 16);
    float rem = a - __uint_as_float(hr);
    unsigned v = __float_as_uint(rem);
    l = (unsigned short)((v + 0x7FFFu + ((v >> 16) & 1u)) >> 16);
}

static __device__ __forceinline__ float bf2(unsigned short h, unsigned short l)
{
    return __uint_as_float((unsigned)h << 16) + __uint_as_float((unsigned)l << 16);
}

// ---------------------------------------------------------------------------
// transpose input x (B,3,N) -> x0cm[(b*N+n)*3+v]
// ---------------------------------------------------------------------------
__global__ void xpose_kernel(const float* __restrict__ x, float* __restrict__ x0cm)
{
    int i = blockIdx.x * 256 + threadIdx.x;   // over MROWS
    if (i >= MROWS) return;
    int v = i % 3;
    int bn = i / 3;
    int b = bn >> 11;
    int n = bn & (NPTS - 1);
    x0cm[i] = x[(b * 3 + v) * NPTS + n];
}

// ---------------------------------------------------------------------------
// KNN: one WAVE per query (no __syncthreads, no LDS).
// ---------------------------------------------------------------------------
__global__ __launch_bounds__(256) void knn_kernel(const float* __restrict__ x, int* __restrict__ idx)
{
    const int wave = threadIdx.x >> 6;
    const int t    = threadIdx.x & 63;
    const int bn   = blockIdx.x * 4 + wave;   // query id
    const int b = bn >> 11;
    const int n = bn & (NPTS - 1);
    const float* xb = x + b * 3 * NPTS;
    const float qx = xb[n], qy = xb[NPTS + n], qz = xb[2 * NPTS + n];
    const float sqn = fmaf(qz, qz, fmaf(qy, qy, qx * qx));

    unsigned key[32];
#pragma unroll
    for (int i = 0; i < 32; i++) {
        int m = (i << 6) + t;
        float mx = xb[m], my = xb[NPTS + m], mz = xb[2 * NPTS + m];
        float sqm = fmaf(mz, mz, fmaf(my, my, mx * mx));
        float dt  = fmaf(qz, mz, fmaf(qy, my, qx * mx));
        float d2  = sqn + sqm - 2.0f * dt;
        unsigned u = __float_as_uint(d2);
        u ^= (u & 0x80000000u) ? 0xFFFFFFFFu : 0x80000000u;  // monotone map
        key[i] = u;
    }
    unsigned lm = key[0];
#pragma unroll
    for (int i = 1; i < 32; i++) lm = min(lm, key[i]);

    int res = -1;
    for (int r = 0; r < KNN_K; r++) {
        unsigned wmin = lm;
#pragma unroll
        for (int off = 32; off > 0; off >>= 1)
            wmin = min(wmin, (unsigned)__shfl_xor((int)wmin, off, 64));

        unsigned cand = 0xFFFFFFFFu;
        int imin = 0;
        if (lm == wmin) {
            imin = 32;
#pragma unroll
            for (int i = 31; i >= 0; i--) if (key[i] == wmin) imin = i;
            cand = (unsigned)((imin << 6) | t);
        }
        unsigned mwin = cand;
#pragma unroll
        for (int off = 32; off > 0; off >>= 1)
            mwin = min(mwin, (unsigned)__shfl_xor((int)mwin, off, 64));

        if (cand == mwin) {            // exactly one owner lane
#pragma unroll
            for (int i = 0; i < 32; i++) if (i == imin) key[i] = 0xFFFFFFFFu;
            lm = key[0];
#pragma unroll
            for (int i = 1; i < 32; i++) lm = min(lm, key[i]);
        }
        if (t == r) res = (int)mwin;
    }
    if (t < KNN_K) idx[bn * KNN_K + t] = res;
}

// ---------------------------------------------------------------------------
// fp32 edge-layer weight for layer 1 only: [4*O, C]
// ---------------------------------------------------------------------------
__global__ void build_wbig(const float* __restrict__ Wf, const float* __restrict__ Wd,
                           float* __restrict__ out, int O, int C)
{
    int i = blockIdx.x * 256 + threadIdx.x;
    int total = 4 * O * C;
    if (i >= total) return;
    int c = i % C;
    int j = i / C;
    int g = j / O;
    int o = j % O;
    float v;
    if (g == 0)      v = Wf[o * 2 * C + c];
    else if (g == 1) v = Wf[o * 2 * C + C + c] - Wf[o * 2 * C + c];
    else if (g == 2) v = Wd[o * 2 * C + c];
    else             v = Wd[o * 2 * C + C + c] - Wd[o * 2 * C + c];
    out[i] = v;
}

// bf16-pair edge-layer weight: [4*O, Kpad], zero-padded cols C..Kpad
__global__ void build_wbig_bf16(const float* __restrict__ Wf, const float* __restrict__ Wd,
                                unsigned short* __restrict__ Wh, unsigned short* __restrict__ Wl,
                                int O, int C, int Kpad)
{
    int i = blockIdx.x * 256 + threadIdx.x;
    int total = 4 * O * Kpad;
    if (i >= total) return;
    int c = i % Kpad;
    int j = i / Kpad;
    int g = j / O;
    int o = j % O;
    float v = 0.f;
    if (c < C) {
        if (g == 0)      v = Wf[o * 2 * C + c];
        else if (g == 1) v = Wf[o * 2 * C + C + c] - Wf[o * 2 * C + c];
        else if (g == 2) v = Wd[o * 2 * C + c];
        else             v = Wd[o * 2 * C + C + c] - Wd[o * 2 * C + c];
    }
    unsigned short h, l;
    split_bf16(v, h, l);
    Wh[i] = h; Wl[i] = l;
}

// stack two weight matrices [Oa,K],[Ob,K] into bf16-pair [Ot, Kpad] (zero pad)
__global__ void build_stack_bf16(const float* __restrict__ Wa, int Oa,
                                 const float* __restrict__ Wb, int Ob, int K,
                                 unsigned short* __restrict__ Wh, unsigned short* __restrict__ Wl,
                                 int Ot, int Kpad)
{
    int i = blockIdx.x * 256 + threadIdx.x;
    if (i >= Ot * Kpad) return;
    int r = i / Kpad;
    int c = i % Kpad;
    float v = 0.f;
    if (c < K) {
        if (r < Oa) v = Wa[r * K + c];
        else if (r < Oa + Ob) v = Wb[(r - Oa) * K + c];
    }
    unsigned short h, l;
    split_bf16(v, h, l);
    Wh[i] = h; Wl[i] = l;
}

// ---------------------------------------------------------------------------
// fp32 GEMM (NT) for layer 1 only (K=1): OUT[m,o] = X[m]*W[o]
// ---------------------------------------------------------------------------
__global__ __launch_bounds__(256) void gemm_l1(const float* __restrict__ X,
                                               const float* __restrict__ W,
                                               float* __restrict__ OUT)
{
    __shared__ float ws[64];
    const int tid = threadIdx.x;
    if (tid < 64) ws[tid] = W[tid];
    __syncthreads();
    const int row = blockIdx.x * 4 + (tid >> 6);  // 4 rows/block
    const int o = tid & 63;
    OUT[row * 64 + o] = X[row] * ws[o];
}

// ---------------------------------------------------------------------------
// Split-bf16 MFMA GEMM (NT): OUT[m,o] = sum_k X[m,xoff+k]*W[o,k]
// X as bf16 hi/lo [MROWS, ldx]; W as bf16 hi/lo [Nw, Kpad] (zero-padded).
// Block: 256 thr = 4 waves; tile 256M x 64N; wave tile 64M x 64N; BK=32.
// A-frags direct from global (L2-resident, wave-private rows);
// W staged in LDS (stride 56 ushort = 112B: rows 0..7 cover all 32 banks).
// mfma 16x16x32_bf16; products hh + hl + lh (ll dropped, ~2^-18).
// ---------------------------------------------------------------------------
__global__ __launch_bounds__(256) void gemm_mfma(
    const unsigned short* __restrict__ Xh, const unsigned short* __restrict__ Xl,
    int ldx, int xoff,
    const unsigned short* __restrict__ Wh, const unsigned short* __restrict__ Wl,
    float* __restrict__ OUT, int ldo, int Nout, int Kpad)
{
    __shared__ unsigned short Ws[2][64][56];
    const int tid = threadIdx.x;
    const int bm = blockIdx.x * 256;
    const int bo = blockIdx.y * 64;
    const int lane = tid & 63;
    const int wv = tid >> 6;
    const int mr = lane & 15;
    const int q  = lane >> 4;

    f32x4 acc[4][4];
#pragma unroll
    for (int a = 0; a < 4; a++)
#pragma unroll
        for (int c = 0; c < 4; c++) acc[a][c] = (f32x4){0.f, 0.f, 0.f, 0.f};

    const int wr = tid >> 2;   // 0..63
    const int sc = tid & 3;    // k-chunk 0..3

    for (int k0 = 0; k0 < Kpad; k0 += 32) {
        // stage W tile (64 rows x 32 k, hi+lo)
        {
            const uint4 vh = *(const uint4*)(Wh + (size_t)(bo + wr) * Kpad + k0 + sc * 8);
            const uint4 vl = *(const uint4*)(Wl + (size_t)(bo + wr) * Kpad + k0 + sc * 8);
            *(uint4*)&Ws[0][wr][sc * 8] = vh;
            *(uint4*)&Ws[1][wr][sc * 8] = vl;
        }
        __syncthreads();

        // A frags direct from global
        bf16x8 ah[4], al[4], bh[4], bl[4];
#pragma unroll
        for (int mf = 0; mf < 4; mf++) {
            const size_t xrow = (size_t)(bm + wv * 64 + mf * 16 + mr) * ldx + xoff + k0 + q * 8;
            ah[mf] = *(const bf16x8*)(Xh + xrow);
            al[mf] = *(const bf16x8*)(Xl + xrow);
        }
#pragma unroll
        for (int nf = 0; nf < 4; nf++) {
            bh[nf] = *(const bf16x8*)&Ws[0][nf * 16 + mr][q * 8];
            bl[nf] = *(const bf16x8*)&Ws[1][nf * 16 + mr][q * 8];
        }
#pragma unroll
        for (int mf = 0; mf < 4; mf++)
#pragma unroll
            for (int nf = 0; nf < 4; nf++) {
                acc[mf][nf] = __builtin_amdgcn_mfma_f32_16x16x32_bf16(ah[mf], bh[nf], acc[mf][nf], 0, 0, 0);
                acc[mf][nf] = __builtin_amdgcn_mfma_f32_16x16x32_bf16(ah[mf], bl[nf], acc[mf][nf], 0, 0, 0);
                acc[mf][nf] = __builtin_amdgcn_mfma_f32_16x16x32_bf16(al[mf], bh[nf], acc[mf][nf], 0, 0, 0);
            }
        __syncthreads();
    }

    // epilogue: D layout col=lane&15, row=q*4+i
#pragma unroll
    for (int nf = 0; nf < 4; nf++) {
        const int col = bo + nf * 16 + mr;
        if (col < Nout) {
#pragma unroll
            for (int mf = 0; mf < 4; mf++) {
#pragma unroll
                for (int i = 0; i < 4; i++) {
                    const int row = bm + wv * 64 + mf * 16 + q * 4 + i;
                    OUT[(size_t)row * ldo + col] = acc[mf][nf][i];
                }
            }
        }
    }
}

// ---------------------------------------------------------------------------
// Edge conv + vec_lna + mean over K neighbors -> bf16 hi/lo output (ld 256)
// AG: [MROWS, 4*O] fp32 = [AF | GF | AD | GD]
// ---------------------------------------------------------------------------
template <int O, int PT>
__global__ __launch_bounds__(256) void edge_kernel(const float* __restrict__ AG,
                                                   const int* __restrict__ idx,
                                                   unsigned short* __restrict__ outh,
                                                   unsigned short* __restrict__ outl,
                                                   int ooff)
{
    const int tid = threadIdx.x;
    const int o = tid % O;
    const int pt = tid / O;
    const int gp = blockIdx.x * PT + pt;
    const int b = gp >> 11;
    __shared__ int sIdx[PT][KNN_K];
    if (tid < PT * KNN_K) {
        sIdx[tid >> 4][tid & 15] = idx[(blockIdx.x * PT + (tid >> 4)) * KNN_K + (tid & 15)];
    }
    __syncthreads();
    const int ld = 4 * O;
    const int rown = gp * 3;
    const float GF0 = AG[(rown + 0) * ld + O + o];
    const float GF1 = AG[(rown + 1) * ld + O + o];
    const float GF2 = AG[(rown + 2) * ld + O + o];
    const float GD0 = AG[(rown + 0) * ld + 3 * O + o];
    const float GD1 = AG[(rown + 1) * ld + 3 * O + o];
    const float GD2 = AG[(rown + 2) * ld + 3 * O + o];
    float a0 = 0.f, a1 = 0.f, a2 = 0.f;
    const int bbase = (b << 11) * 3;
#pragma unroll
    for (int k = 0; k < KNN_K; k++) {
        int m = sIdx[pt][k];
        const float* base = AG + (bbase + m * 3) * ld + o;
        float p0 = base[0]           + GF0;
        float d0 = base[2 * O]       + GD0;
        float p1 = base[ld]          + GF1;
        float d1 = base[ld + 2 * O]  + GD1;
        float p2 = base[2 * ld]          + GF2;
        float d2 = base[2 * ld + 2 * O]  + GD2;
        float dot = fmaf(p2, d2, fmaf(p1, d1, p0 * d0));
        float dsq = fmaf(d2, d2, fmaf(d1, d1, d0 * d0));
        float s = (dot < 0.f) ? 0.8f * dot / (dsq + 1e-6f) : 0.f;
        a0 += fmaf(-s, d0, p0);
        a1 += fmaf(-s, d1, p1);
        a2 += fmaf(-s, d2, p2);
    }
    float r[3] = { a0 * 0.0625f, a1 * 0.0625f, a2 * 0.0625f };
#pragma unroll
    for (int v = 0; v < 3; v++) {
        unsigned short h, l;
        split_bf16(r[v], h, l);
        outh[(rown + v) * 256 + ooff + o] = h;
        outl[(rown + v) * 256 + ooff + o] = l;
    }
}

// ---------------------------------------------------------------------------
// vec_lna for wc: PD [MROWS,132] fp32 (p=0..127, d=col 128) -> xc2 pair cols 0..127
// ---------------------------------------------------------------------------
__global__ __launch_bounds__(256) void lna_wc_kernel(const float* __restrict__ PD,
                                                     unsigned short* __restrict__ oh,
                                                     unsigned short* __restrict__ ol)
{
    const int tid = threadIdx.x;
    const int o = tid & 127;
    const int pt = tid >> 7;
    const int gp = blockIdx.x * 2 + pt;
    const int row = gp * 3;
    const float d0 = PD[(row + 0) * 132 + 128];
    const float d1 = PD[(row + 1) * 132 + 128];
    const float d2 = PD[(row + 2) * 132 + 128];
    const float dsq = fmaf(d2, d2, fmaf(d1, d1, d0 * d0));
    const float p0 = PD[(row + 0) * 132 + o];
    const float p1 = PD[(row + 1) * 132 + o];
    const float p2 = PD[(row + 2) * 132 + o];
    const float dot = fmaf(p2, d2, fmaf(p1, d1, p0 * d0));
    const float s = (dot < 0.f) ? 0.8f * dot / (dsq + 1e-6f) : 0.f;
    float r[3] = { fmaf(-s, d0, p0), fmaf(-s, d1, p1), fmaf(-s, d2, p2) };
#pragma unroll
    for (int v = 0; v < 3; v++) {
        unsigned short h, l;
        split_bf16(r[v], h, l);
        oh[(row + v) * 256 + o] = h;
        ol[(row + v) * 256 + o] = l;
    }
}

// vec_lna generic: PD [MROWS,256] fp32 (p=0..127, d=128..255) -> y1 pair (ld 128)
__global__ __launch_bounds__(256) void lna_128_kernel(const float* __restrict__ PD,
                                                      unsigned short* __restrict__ oh,
                                                      unsigned short* __restrict__ ol)
{
    const int tid = threadIdx.x;
    const int o = tid & 127;
    const int pt = tid >> 7;
    const int gp = blockIdx.x * 2 + pt;
    const int row = gp * 3;
    float p[3], d[3];
#pragma unroll
    for (int v = 0; v < 3; v++) {
        p[v] = PD[(row + v) * 256 + o];
        d[v] = PD[(row + v) * 256 + 128 + o];
    }
    float dot = fmaf(p[2], d[2], fmaf(p[1], d[1], p[0] * d[0]));
    float dsq = fmaf(d[2], d[2], fmaf(d[1], d[1], d[0] * d[0]));
    float s = (dot < 0.f) ? 0.8f * dot / (dsq + 1e-6f) : 0.f;
#pragma unroll
    for (int v = 0; v < 3; v++) {
        unsigned short h, l;
        split_bf16(fmaf(-s, d[v], p[v]), h, l);
        oh[(row + v) * 128 + o] = h;
        ol[(row + v) * 128 + o] = l;
    }
}

// ---------------------------------------------------------------------------
// xm = mean over n of xc2 cols 0..127 -> broadcast into cols 128..255
// ---------------------------------------------------------------------------
__global__ void xm_partial_kernel(const unsigned short* __restrict__ xh,
                                  const unsigned short* __restrict__ xl,
                                  float* __restrict__ part)
{
    const int g = blockIdx.x;        // B*3*32 = 384
    const int s = g & 31;
    const int bv = g >> 5;           // 0..11  (b*3+v)
    const int b = bv / 3;
    const int v = bv % 3;
    const int o = threadIdx.x;       // 128
    float acc = 0.f;
    for (int i = 0; i < 64; i++) {
        int n = s * 64 + i;
        size_t ix = (size_t)((b * NPTS + n) * 3 + v) * 256 + o;
        acc += bf2(xh[ix], xl[ix]);
    }
    part[(bv * 32 + s) * 128 + o] = acc;
}

__global__ void xm_final_kernel(const float* __restrict__ part, float* __restrict__ xm)
{
    const int bv = blockIdx.x;       // 12
    const int o = threadIdx.x;       // 128
    float acc = 0.f;
    for (int i = 0; i < 32; i++) acc += part[(bv * 32 + i) * 128 + o];
    xm[bv * 128 + o] = acc * (1.f / 2048.f);
}

__global__ void xm_bcast_kernel(const float* __restrict__ xm,
                                unsigned short* __restrict__ xh,
                                unsigned short* __restrict__ xl)
{
    int i = blockIdx.x * 256 + threadIdx.x;   // MROWS*128
    int row = i >> 7;
    int o = i & 127;
    int b = row / (3 * NPTS);
    int v = row % 3;
    unsigned short h, l;
    split_bf16(xm[(b * 3 + v) * 128 + o], h, l);
    xh[(size_t)row * 256 + 128 + o] = h;
    xl[(size_t)row * 256 + 128 + o] = l;
}

// ---------------------------------------------------------------------------
// final: vec_lna(wi2 PD) fused with inv = sum_v xcat2 * x0, LDS transpose
// ---------------------------------------------------------------------------
__global__ __launch_bounds__(256) void final_inv_kernel(const float* __restrict__ PD2,
                                                        const unsigned short* __restrict__ xch,
                                                        const unsigned short* __restrict__ xcl,
                                                        float* __restrict__ out)
{
    __shared__ float sh[32][257];
    const int tid = threadIdx.x;     // o = tid, 0..255
    const int base_gp = blockIdx.x * 32;
    const int b = base_gp >> 11;
    const int n0 = base_gp & (NPTS - 1);
    for (int pt = 0; pt < 32; pt++) {
        const int row = (base_gp + pt) * 3;
        float p[3], d[3], xc[3];
#pragma unroll
        for (int v = 0; v < 3; v++) {
            p[v]  = PD2[(size_t)(row + v) * 512 + tid];
            d[v]  = PD2[(size_t)(row + v) * 512 + 256 + tid];
            size_t ix = (size_t)(row + v) * 256 + tid;
            xc[v] = bf2(xch[ix], xcl[ix]);
        }
        float dot = fmaf(p[2], d[2], fmaf(p[1], d[1], p[0] * d[0]));
        float dsq = fmaf(d[2], d[2], fmaf(d[1], d[1], d[0] * d[0]));
        float s = (dot < 0.f) ? 0.8f * dot / (dsq + 1e-6f) : 0.f;
        float inv = 0.f;
#pragma unroll
        for (int v = 0; v < 3; v++) {
            inv = fmaf(xc[v], fmaf(-s, d[v], p[v]), inv);
        }
        sh[pt][tid] = inv;
    }
    __syncthreads();
#pragma unroll
    for (int j = 0; j < 32; j++) {
        int ow = (tid >> 5) + j * 8;
        int pt2 = tid & 31;
        out[((size_t)b * 256 + ow) * NPTS + n0 + pt2] = sh[pt2][ow];
    }
}

// ---------------------------------------------------------------------------
// launch
// ---------------------------------------------------------------------------
extern "C" void kernel_launch(void* const* d_in, const int* in_sizes, int n_in,
                              void* d_out, int out_size, void* d_ws, size_t ws_size,
                              hipStream_t stream)
{
    const float* x    = (const float*)d_in[0];
    const float* w1f  = (const float*)d_in[1];
    const float* w1d  = (const float*)d_in[2];
    const float* w2f  = (const float*)d_in[3];
    const float* w2d  = (const float*)d_in[4];
    const float* w3f  = (const float*)d_in[5];
    const float* w3d  = (const float*)d_in[6];
    const float* w4f  = (const float*)d_in[7];
    const float* w4d  = (const float*)d_in[8];
    const float* wcf  = (const float*)d_in[9];
    const float* wcd  = (const float*)d_in[10];
    const float* wi1f = (const float*)d_in[11];
    const float* wi1d = (const float*)d_in[12];
    const float* wi2f = (const float*)d_in[13];
    const float* wi2d = (const float*)d_in[14];
    float* out = (float*)d_out;

    float* F = (float*)d_ws;
    size_t off = 0;
    float* AG = F + off;                          off += (size_t)MROWS * 512;  // fp32 PD buffer
    unsigned short* X240h = (unsigned short*)(F + off); off += (size_t)MROWS * 128; // MROWS*256 u16
    unsigned short* X240l = (unsigned short*)(F + off); off += (size_t)MROWS * 128;
    unsigned short* xc2h  = (unsigned short*)(F + off); off += (size_t)MROWS * 128;
    unsigned short* xc2l  = (unsigned short*)(F + off); off += (size_t)MROWS * 128;
    float* x0cm = F + off;                        off += MROWS;
    float* Wb1  = F + off;                        off += 64;
    unsigned short* Wb2h = (unsigned short*)(F + off); off += 2048;   // 128*32 u16
    unsigned short* Wb2l = (unsigned short*)(F + off); off += 2048;
    unsigned short* Wb3h = (unsigned short*)(F + off); off += 4096;   // 256*32
    unsigned short* Wb3l = (unsigned short*)(F + off); off += 4096;
    unsigned short* Wb4h = (unsigned short*)(F + off); off += 16384;  // 512*64
    unsigned short* Wb4l = (unsigned short*)(F + off); off += 16384;
    unsigned short* Wch  = (unsigned short*)(F + off); off += 24576;  // 192*256
    unsigned short* Wcl  = (unsigned short*)(F + off); off += 24576;
    unsigned short* Wi1h = (unsigned short*)(F + off); off += 32768;  // 256*256
    unsigned short* Wi1l = (unsigned short*)(F + off); off += 32768;
    unsigned short* Wi2h = (unsigned short*)(F + off); off += 32768;  // 512*128
    unsigned short* Wi2l = (unsigned short*)(F + off); off += 32768;
    float* part = F + off;                        off += 12 * 32 * 128;
    float* xm   = F + off;                        off += 12 * 128;
    int* idx    = (int*)(F + off);                off += NBP * KNN_K;
    unsigned short* y1h = X240h;   // alias: X240 dead after wc GEMM
    unsigned short* y1l = X240l;

    // prep
    xpose_kernel<<<MROWS / 256, 256, 0, stream>>>(x, x0cm);
    knn_kernel<<<NBP / 4, 256, 0, stream>>>(x, idx);
    build_wbig<<<1, 256, 0, stream>>>(w1f, w1d, Wb1, 16, 1);
    build_wbig_bf16<<<16, 256, 0, stream>>>(w2f, w2d, Wb2h, Wb2l, 32, 16, 32);
    build_wbig_bf16<<<32, 256, 0, stream>>>(w3f, w3d, Wb3h, Wb3l, 64, 32, 32);
    build_wbig_bf16<<<128, 256, 0, stream>>>(w4f, w4d, Wb4h, Wb4l, 128, 64, 64);
    build_stack_bf16<<<192, 256, 0, stream>>>(wcf, 128, wcd, 1, 240, Wch, Wcl, 192, 256);
    build_stack_bf16<<<256, 256, 0, stream>>>(wi1f, 128, wi1d, 128, 256, Wi1h, Wi1l, 256, 256);
    build_stack_bf16<<<256, 256, 0, stream>>>(wi2f, 256, wi2d, 256, 128, Wi2h, Wi2l, 512, 128);

    const int GM = MROWS / 256;   // 96

    // layer 1: K=1, O=16 (fp32 trivial GEMM)
    gemm_l1<<<MROWS / 4, 256, 0, stream>>>(x0cm, Wb1, AG);
    edge_kernel<16, 16><<<NBP / 16, 256, 0, stream>>>(AG, idx, X240h, X240l, 0);
    // layer 2: K=16 (pad 32), O=32
    gemm_mfma<<<dim3(GM, 2), 256, 0, stream>>>(X240h, X240l, 256, 0, Wb2h, Wb2l, AG, 128, 128, 32);
    edge_kernel<32, 8><<<NBP / 8, 256, 0, stream>>>(AG, idx, X240h, X240l, 16);
    // layer 3: K=32, O=64
    gemm_mfma<<<dim3(GM, 4), 256, 0, stream>>>(X240h, X240l, 256, 16, Wb3h, Wb3l, AG, 256, 256, 32);
    edge_kernel<64, 4><<<NBP / 4, 256, 0, stream>>>(AG, idx, X240h, X240l, 48);
    // layer 4: K=64, O=128
    gemm_mfma<<<dim3(GM, 8), 256, 0, stream>>>(X240h, X240l, 256, 48, Wb4h, Wb4l, AG, 512, 512, 64);
    edge_kernel<128, 2><<<NBP / 2, 256, 0, stream>>>(AG, idx, X240h, X240l, 112);

    // wc: K=240 (pad 256) -> PD [MROWS,132]
    gemm_mfma<<<dim3(GM, 3), 256, 0, stream>>>(X240h, X240l, 256, 0, Wch, Wcl, AG, 132, 132, 256);
    lna_wc_kernel<<<NBP / 2, 256, 0, stream>>>(AG, xc2h, xc2l);

    // xm mean + broadcast
    xm_partial_kernel<<<BATCH * 3 * 32, 128, 0, stream>>>(xc2h, xc2l, part);
    xm_final_kernel<<<BATCH * 3, 128, 0, stream>>>(part, xm);
    xm_bcast_kernel<<<(MROWS * 128) / 256, 256, 0, stream>>>(xm, xc2h, xc2l);

    // wi1: K=256 -> PD [MROWS,256] -> y1 pair
    gemm_mfma<<<dim3(GM, 4), 256, 0, stream>>>(xc2h, xc2l, 256, 0, Wi1h, Wi1l, AG, 256, 256, 256);
    lna_128_kernel<<<NBP / 2, 256, 0, stream>>>(AG, y1h, y1l);

    // wi2: K=128 -> PD [MROWS,512] -> fused lna + inv + transpose
    gemm_mfma<<<dim3(GM, 8), 256, 0, stream>>>(y1h, y1l, 128, 0, Wi2h, Wi2l, AG, 512, 512, 128);
    final_inv_kernel<<<NBP / 32, 256, 0, stream>>>(AG, xc2h, xc2l, out);

    (void)in_sizes; (void)n_in; (void)out_size; (void)ws_size;
}